// Round 4
// baseline (423.946 us; speedup 1.0000x reference)
//
#include <hip/hip_runtime.h>
#include <stdint.h>

typedef __bf16 bf16;
typedef __bf16 bf16x4 __attribute__((ext_vector_type(4)));
typedef __bf16 bf16x8 __attribute__((ext_vector_type(8)));
typedef float floatx4 __attribute__((ext_vector_type(4)));

#define B_   2
#define T_   2048
#define E_   2048
#define G_   4
#define QPG_ 4
#define D_   128
#define H_   16        // G*QPG
#define NQ   2048      // H*D
#define NKV  1024      // 2*G*D
#define NQKV 3072
#define M_   4096      // B*T

// async global->LDS, 16B/lane; LDS dst is wave-uniform base + lane*16
__device__ __forceinline__ void gload_lds16(const void* g, void* l) {
  __builtin_amdgcn_global_load_lds(
      (__attribute__((address_space(1))) unsigned int*)g,
      (__attribute__((address_space(3))) unsigned int*)l,
      16, 0, 0);
}

// ---- LDS XOR swizzle for [row][32-elem] tiles staged via global_load_lds ----
// Slot s (16B) of row R holds global chunk s ^ (R&3) ^ ((R>>2)&3).
// Staging: lane L covers (row = base + L/4); it must FETCH global chunk
//   (L&3) ^ ((L>>2)&3) ^ ((L>>4)&3)   [since LDS slot of lane L is L&3].
// Reading chunk q of row R': elem offset = (q ^ (c&3) ^ ((c>>2)&3)) * 8.
// Result: worst case 2 lanes/bank per b128 phase == conflict-free (m136).
__device__ __forceinline__ int swz_stage_col(int lane) {
  return (((lane & 3) ^ ((lane >> 2) & 3) ^ ((lane >> 4) & 3))) * 8;
}

// ---------------- conversion kernels ----------------

__global__ void cast_f32_bf16(const float* __restrict__ in, bf16* __restrict__ out, int n4) {
  int i = blockIdx.x * blockDim.x + threadIdx.x;
  if (i < n4) {
    float4 v = ((const float4*)in)[i];
    bf16x4 o = {(bf16)v.x, (bf16)v.y, (bf16)v.z, (bf16)v.w};
    ((bf16x4*)out)[i] = o;
  }
}

// in: R x C f32 (row-major). out: C x R bf16, row stride out_stride.
__global__ void transpose_cast(const float* __restrict__ in, bf16* __restrict__ out,
                               int R, int C, int out_stride) {
  __shared__ float tile[64][65];
  int r0 = blockIdx.x * 64, c0 = blockIdx.y * 64;
  int tx = threadIdx.x & 63, ty = threadIdx.x >> 6;
  for (int i = ty; i < 64; i += 4)
    tile[i][tx] = in[(size_t)(r0 + i) * C + c0 + tx];
  __syncthreads();
  for (int i = ty; i < 64; i += 4)
    out[(size_t)(c0 + i) * out_stride + r0 + tx] = (bf16)tile[tx][i];
}

__global__ void concat_bias(const float* __restrict__ bq, const float* __restrict__ bkv,
                            float* __restrict__ out) {
  int i = blockIdx.x * 256 + threadIdx.x;  // grid covers exactly 3072
  out[i] = (i < NQ) ? bq[i] : bkv[i - NQ];
}

// ---------------- GEMM: C = A(MxK) * Bt(NxK)^T (+bias) ----------------
// m97 structure: 128x128 tile, BK=32, global_load_lds width16, 16x16x32 MFMA,
// + XOR-swizzled LDS chunks (removes the 8-way bank conflict of stride-64B rows).

template <int OUT_BF16, int HAS_BIAS>
__global__ __launch_bounds__(256, 2) void gemm_bt(
    const bf16* __restrict__ A, const bf16* __restrict__ Bt,
    const float* __restrict__ bias, void* __restrict__ Cout,
    int M, int N, int K) {
  __shared__ __align__(16) bf16 As[128 * 32];
  __shared__ __align__(16) bf16 Bs[128 * 32];
  const int tid = threadIdx.x;
  const int wave = tid >> 6, lane = tid & 63;
  const int quad = lane >> 4, c = lane & 15;
  const int m0 = blockIdx.x * 128, n0 = blockIdx.y * 128;
  const int wr = (wave >> 1) * 64, wc = (wave & 1) * 64;
  const int xsl = ((quad ^ (c & 3) ^ ((c >> 2) & 3)) & 3) * 8;  // swizzled read slot

  floatx4 acc[4][4];
#pragma unroll
  for (int i = 0; i < 4; ++i)
#pragma unroll
    for (int j = 0; j < 4; ++j) acc[i][j] = (floatx4){0.f, 0.f, 0.f, 0.f};

  // staging: chunk = wave*2+ch covers 16 rows; lane -> row L/4, col swizzled
  const int srow = wave * 32 + (lane >> 2);
  const int scol = swz_stage_col(lane);
  const bf16* Ap = A + (size_t)(m0 + srow) * K + scol;
  const bf16* Bp = Bt + (size_t)(n0 + srow) * K + scol;

  for (int k0 = 0; k0 < K; k0 += 32) {
#pragma unroll
    for (int ch = 0; ch < 2; ++ch) {
      gload_lds16(Ap + (size_t)ch * 16 * K + k0, &As[(wave * 2 + ch) * 512]);
      gload_lds16(Bp + (size_t)ch * 16 * K + k0, &Bs[(wave * 2 + ch) * 512]);
    }
    __syncthreads();
    bf16x8 af[4], bfr[4];
#pragma unroll
    for (int i = 0; i < 4; ++i) {
      af[i]  = *(const bf16x8*)(&As[(wr + i * 16 + c) * 32 + xsl]);
      bfr[i] = *(const bf16x8*)(&Bs[(wc + i * 16 + c) * 32 + xsl]);
    }
#pragma unroll
    for (int mi = 0; mi < 4; ++mi)
#pragma unroll
      for (int ni = 0; ni < 4; ++ni)
        acc[mi][ni] = __builtin_amdgcn_mfma_f32_16x16x32_bf16(af[mi], bfr[ni], acc[mi][ni], 0, 0, 0);
    __syncthreads();
  }

  float bv[4] = {0.f, 0.f, 0.f, 0.f};
  if (HAS_BIAS) {
#pragma unroll
    for (int ni = 0; ni < 4; ++ni) bv[ni] = bias[n0 + wc + ni * 16 + c];
  }
#pragma unroll
  for (int mi = 0; mi < 4; ++mi) {
#pragma unroll
    for (int ni = 0; ni < 4; ++ni) {
      const int col = n0 + wc + ni * 16 + c;
#pragma unroll
      for (int r = 0; r < 4; ++r) {
        const int row = m0 + wr + mi * 16 + quad * 4 + r;  // C-layout: row=quad*4+reg
        float v = acc[mi][ni][r] + bv[ni];
        if (OUT_BF16)
          ((bf16*)Cout)[(size_t)row * N + col] = (bf16)v;
        else
          ((float*)Cout)[(size_t)row * N + col] = v;
      }
    }
  }
}

// ---------------- PE + layout scatter ----------------

__device__ __forceinline__ float pe_val(int t, int d) {
  int i2 = d & ~1;
  float inv = __expf(-9.210340371976184f * (float)i2 * (1.0f / 128.0f));
  float ang = (float)t * inv;
  return (d & 1) ? cosf(ang) : sinf(ang);
}

// Q[b][h][t][d] = (qkv[.., h*D+d] + pe) * log2(e)/sqrt(D)   (exp2-domain fold)
// K[b][g][t][d] =  qkv[.., 2048 + g*256 + d] + pe
__global__ void scatter_qk(const bf16* __restrict__ qkv,
                           bf16* __restrict__ Qb, bf16* __restrict__ Kb) {
  const int row = blockIdx.x;  // 0..4095
  const int b = row >> 11, t = row & 2047;
  const int tid = threadIdx.x;
  const int d = tid & 127;
  const float scale = 0.12751745f;  // log2(e)/sqrt(128)
  const float pe = pe_val(t, d);
  for (int h = tid >> 7; h < H_; h += 2) {
    float q = (float)qkv[(size_t)row * NQKV + h * 128 + d] + pe;
    Qb[((size_t)(b * H_ + h) * T_ + t) * D_ + d] = (bf16)(q * scale);
  }
  for (int g = tid >> 7; g < G_; g += 2) {
    float k = (float)qkv[(size_t)row * NQKV + NQ + g * 256 + d] + pe;
    Kb[((size_t)(b * G_ + g) * T_ + t) * D_ + d] = (bf16)k;
  }
}

// Vt[b][g][d][t] = qkv[b*T+t][2048 + g*256 + 128 + d]  (LDS-tiled transpose)
__global__ void build_vt(const bf16* __restrict__ qkv, bf16* __restrict__ Vt) {
  __shared__ float tile[64][65];
  int t0 = blockIdx.x * 64, d0 = blockIdx.y * 64;
  int bg = blockIdx.z, b = bg >> 2, g = bg & 3;
  const bf16* src = qkv + (size_t)b * T_ * NQKV + NQ + g * 256 + 128;
  bf16* dst = Vt + (size_t)bg * D_ * T_;
  int tx = threadIdx.x & 63, ty = threadIdx.x >> 6;
  for (int i = ty; i < 64; i += 4)
    tile[i][tx] = (float)src[(size_t)(t0 + i) * NQKV + d0 + tx];
  __syncthreads();
  for (int i = ty; i < 64; i += 4)
    dst[(size_t)(d0 + i) * T_ + t0 + tx] = (bf16)tile[tx][i];
}

// ---------------- flash attention v8: V direct from L2 ----------------
// v7 was LDS-pipe-bound: 17 b128 reads per 16 MFMAs ~= 104K cyc/CU (55% of
// runtime) + P-writes + 9M conflict cycles. v8 keeps v7's structure but drops
// the V LDS staging entirely: vf fragments are read straight from Vt (global,
// L2/L3-resident 8MB working set) with perfectly line-coalesced 16B/lane
// loads (quads of one c cover one contiguous 64B line). LDS reads per
// tile-wave 17 -> 9; LDS shrinks 75.8KB -> 42KB -> 3 blocks/CU = 24 waves/CU
// (6/SIMD) for more TLP; CU-level block triples + greedy backfill balance
// better than v7's pairs.

__global__ __launch_bounds__(512, 6) void flash_attn(
    const bf16* __restrict__ Qb, const bf16* __restrict__ Kb,
    const bf16* __restrict__ Vt, bf16* __restrict__ Ob) {
  const int i = blockIdx.x;
  const int qt = 31 - (i >> 5);   // longest blocks dispatch first (LPT)
  const int bh = i & 31;
  const int b = bh >> 4, h = bh & 15, g2 = h >> 2;
  const int tid = threadIdx.x;
  const int wave = tid >> 6, lane = tid & 63;
  const int grp = wave >> 2, w4 = wave & 3;   // key-range group, wave-in-group
  const int quad = lane >> 4, c = lane & 15;
  const int xsl = ((quad ^ (c & 3) ^ ((c >> 2) & 3)) & 3) * 8;  // swizzled read slot

  // 43,008 B static LDS; 3 blocks/CU (129,024 <= 163,840)
  __shared__ __align__(16) char smem[43008];
  bf16* Ks = (bf16*)smem;                  // [grp][buf][chunk4][32*32]  32 KB
  bf16* Pq = (bf16*)(smem + 32768);        // [wave8][16*40]             10 KB

  const int q0 = qt * 64;
  const bf16* Qbase = Qb + ((size_t)(b * H_ + h) * T_ + q0 + w4 * 16 + c) * D_;
  bf16x8 qf[4];
#pragma unroll
  for (int ks = 0; ks < 4; ++ks)
    qf[ks] = *(const bf16x8*)(Qbase + ks * 32 + quad * 8);

  floatx4 acc[8];
#pragma unroll
  for (int nd = 0; nd < 8; ++nd) acc[nd] = (floatx4){0.f, 0.f, 0.f, 0.f};
  float rsum[4] = {0.f, 0.f, 0.f, 0.f};

  const bf16* Kg = Kb + (size_t)(b * G_ + g2) * T_ * D_;
  const bf16* Vg = Vt + (size_t)(b * G_ + g2) * D_ * T_;
  const int slr = lane >> 2;               // staging row within 16
  const int slc = swz_stage_col(lane);     // staging col (elems), swizzled
  const int ng = qt + 1;                   // tiles per group
  const int jbase = grp * ng;              // group's first absolute key-tile
  const int amax = 2 * qt + (w4 >> 1);     // wave's last live absolute tile

  // stage absolute key-tile t's K into this group's buffer bu; wave owns chunk w4
  auto stage = [&](int t, int bu) {
    const int k0 = t * 32;
    bf16* kd = Ks + ((grp * 2 + bu) * 4 + w4) * 1024;
#pragma unroll
    for (int hh = 0; hh < 2; ++hh)
      gload_lds16(Kg + (size_t)(k0 + hh * 16 + slr) * D_ + w4 * 32 + slc, kd + hh * 512);
  };

  stage(jbase, 0);

  for (int jg = 0; jg < ng; ++jg) {
    __syncthreads();  // both groups run identical barrier counts (ng each)
    if (jg + 1 < ng) stage(jbase + jg + 1, (jg + 1) & 1);
    const int j = jbase + jg;
    if (j > amax) continue;  // fully masked for this wave: stage+barrier only

    const bf16* Kt = Ks + (grp * 2 + (jg & 1)) * 4096;
    const int k0j = j * 32;

    // S = Q K^T : 16q x 32k per wave (scores already in log2 domain)
    floatx4 s[2];
    s[0] = (floatx4){0.f, 0.f, 0.f, 0.f};
    s[1] = (floatx4){0.f, 0.f, 0.f, 0.f};
#pragma unroll
    for (int ks = 0; ks < 4; ++ks)
#pragma unroll
      for (int n = 0; n < 2; ++n) {
        bf16x8 kf = *(const bf16x8*)(Kt + ks * 1024 + (n * 16 + c) * 32 + xsl);
        s[n] = __builtin_amdgcn_mfma_f32_16x16x32_bf16(qf[ks], kf, s[n], 0, 0, 0);
      }

    if (j == amax) {  // diagonal tile: mask key > qrow (exp2(-1e30) == 0)
      const int colb = j * 32;
      const int rowb = q0 + w4 * 16 + quad * 4;
#pragma unroll
      for (int n = 0; n < 2; ++n)
#pragma unroll
        for (int r = 0; r < 4; ++r)
          if (colb + n * 16 + c > rowb + r) s[n][r] = -1e30f;
    }

    // p = exp2(s); accumulate row-sum; P to LDS in A-layout [q][key]
    bf16* Pw = Pq + wave * 640;
#pragma unroll
    for (int n = 0; n < 2; ++n)
#pragma unroll
      for (int r = 0; r < 4; ++r) {
        float p = exp2f(s[n][r]);
        rsum[r] += p;
        Pw[(quad * 4 + r) * 40 + n * 16 + c] = (bf16)p;
      }

    // A-frag read: one aligned b128  (pf[j] = P[q=c][key=quad*8+j])
    bf16x8 pf = *(const bf16x8*)(&Pw[c * 40 + quad * 8]);

    // O += P(16q x 32k) * V(32k x 128d); vf straight from L2 (coalesced:
    // the 4 quads of one c cover one contiguous 64B line of Vt row d)
#pragma unroll
    for (int nd = 0; nd < 8; ++nd) {
      bf16x8 vf = *(const bf16x8*)(
          Vg + (size_t)((nd >> 1) * 32 + (nd & 1) * 16 + c) * T_ + k0j + quad * 8);
      acc[nd] = __builtin_amdgcn_mfma_f32_16x16x32_bf16(pf, vf, acc[nd], 0, 0, 0);
    }
  }

  // per-group row-sum reduction across the 16 lanes (c) of each quad-row
#pragma unroll
  for (int off = 1; off < 16; off <<= 1)
#pragma unroll
    for (int r = 0; r < 4; ++r) rsum[r] += __shfl_xor(rsum[r], off);

  // ---- in-LDS merge of the two key-range groups (purely additive) ----
  __syncthreads();  // all loop LDS reads done; safe to alias Ks/Pq region
  float* mrg = (float*)smem;               // [2][64][68] f32, 34,816 B
  float* mrs = (float*)(smem + 34816);     // [2][64] f32 row-sums
  const int row16 = w4 * 16 + quad * 4;

  // group g stashes the half it will NOT finalize: half (1-g)
  if (grp == 0) {
#pragma unroll
    for (int nd2 = 0; nd2 < 4; ++nd2)
#pragma unroll
      for (int r = 0; r < 4; ++r)
        mrg[(row16 + r) * 68 + nd2 * 16 + c] = acc[4 + nd2][r];
  } else {
#pragma unroll
    for (int nd2 = 0; nd2 < 4; ++nd2)
#pragma unroll
      for (int r = 0; r < 4; ++r)
        mrg[(64 + row16 + r) * 68 + nd2 * 16 + c] = acc[nd2][r];
  }
  if (c == 0) {
#pragma unroll
    for (int r = 0; r < 4; ++r) mrs[grp * 64 + row16 + r] = rsum[r];
  }
  __syncthreads();

  const int og = grp ^ 1;
  float linv[4];
#pragma unroll
  for (int r = 0; r < 4; ++r) linv[r] = 1.f / (rsum[r] + mrs[og * 64 + row16 + r]);

  if (grp == 0) {  // finalize cols 0..63 (nd 0..3) with group 1's copy
#pragma unroll
    for (int nd2 = 0; nd2 < 4; ++nd2)
#pragma unroll
      for (int r = 0; r < 4; ++r) {
        float o = acc[nd2][r] + mrg[(64 + row16 + r) * 68 + nd2 * 16 + c];
        const int trow = q0 + row16 + r;
        Ob[((size_t)(b * T_ + trow)) * NQ + h * D_ + nd2 * 16 + c] = (bf16)(o * linv[r]);
      }
  } else {         // finalize cols 64..127 (nd 4..7) with group 0's copy
#pragma unroll
    for (int nd2 = 0; nd2 < 4; ++nd2)
#pragma unroll
      for (int r = 0; r < 4; ++r) {
        float o = acc[4 + nd2][r] + mrg[(row16 + r) * 68 + nd2 * 16 + c];
        const int trow = q0 + row16 + r;
        Ob[((size_t)(b * T_ + trow)) * NQ + h * D_ + (4 + nd2) * 16 + c] = (bf16)(o * linv[r]);
      }
  }
}

// ---------------- launch ----------------

extern "C" void kernel_launch(void* const* d_in, const int* in_sizes, int n_in,
                              void* d_out, int out_size, void* d_ws, size_t ws_size,
                              hipStream_t stream) {
  const float* x   = (const float*)d_in[0];
  const float* wq  = (const float*)d_in[1];
  const float* bq  = (const float*)d_in[2];
  const float* wkv = (const float*)d_in[3];
  const float* bkv = (const float*)d_in[4];
  const float* wo  = (const float*)d_in[5];
  float* out = (float*)d_out;

  char* p = (char*)d_ws;                                   // ~100 MB total
  bf16* xb    = (bf16*)p; p += (size_t)M_ * E_ * 2;        // 16 MB
  bf16* wqkvT = (bf16*)p; p += (size_t)NQKV * E_ * 2;      // 12 MB  [N=3072][K=2048]
  bf16* woT   = (bf16*)p; p += (size_t)E_ * NQ * 2;        // 8 MB   [N=2048][K=2048]
  float* biasq = (float*)p; p += 16384;                    // 3072 f32, padded
  bf16* qkv   = (bf16*)p; p += (size_t)M_ * NQKV * 2;      // 24 MB
  bf16* Qb    = (bf16*)p; p += (size_t)B_ * H_ * T_ * D_ * 2;  // 16 MB
  bf16* Kb    = (bf16*)p; p += (size_t)B_ * G_ * T_ * D_ * 2;  // 4 MB
  bf16* Vtb   = (bf16*)p; p += (size_t)B_ * G_ * D_ * T_ * 2;  // 4 MB
  bf16* Ob    = (bf16*)p; p += (size_t)M_ * NQ * 2;            // 16 MB

  cast_f32_bf16<<<(M_ * E_ / 4) / 256, 256, 0, stream>>>(x, xb, M_ * E_ / 4);
  transpose_cast<<<dim3(E_ / 64, E_ / 64), 256, 0, stream>>>(wq, wqkvT, E_, E_, E_);
  transpose_cast<<<dim3(E_ / 64, NKV / 64), 256, 0, stream>>>(wkv, wqkvT + (size_t)NQ * E_, E_, NKV, E_);
  transpose_cast<<<dim3(E_ / 64, E_ / 64), 256, 0, stream>>>(wo, woT, NQ, E_, NQ);
  concat_bias<<<NQKV / 256, 256, 0, stream>>>(bq, bkv, biasq);

  gemm_bt<1, 1><<<dim3(M_ / 128, NQKV / 128), 256, 0, stream>>>(xb, wqkvT, biasq, qkv, M_, NQKV, E_);
  scatter_qk<<<M_, 256, 0, stream>>>(qkv, Qb, Kb);
  build_vt<<<dim3(T_ / 64, D_ / 64, B_ * G_), 256, 0, stream>>>(qkv, Vtb);
  flash_attn<<<1024, 512, 0, stream>>>(Qb, Kb, Vtb, Ob);
  gemm_bt<0, 0><<<dim3(M_ / 128, E_ / 128), 256, 0, stream>>>(Ob, woT, nullptr, out, M_, E_, NQ);
}

// Round 5
// 364.948 us; speedup vs baseline: 1.1617x; 1.1617x over previous
//
#include <hip/hip_runtime.h>
#include <stdint.h>

typedef __bf16 bf16;
typedef __bf16 bf16x4 __attribute__((ext_vector_type(4)));
typedef __bf16 bf16x8 __attribute__((ext_vector_type(8)));
typedef float floatx4 __attribute__((ext_vector_type(4)));

#define B_   2
#define T_   2048
#define E_   2048
#define G_   4
#define QPG_ 4
#define D_   128
#define H_   16        // G*QPG
#define NQ   2048      // H*D
#define NKV  1024      // 2*G*D
#define NQKV 3072
#define M_   4096      // B*T

// async global->LDS, 16B/lane; LDS dst is wave-uniform base + lane*16
__device__ __forceinline__ void gload_lds16(const void* g, void* l) {
  __builtin_amdgcn_global_load_lds(
      (__attribute__((address_space(1))) unsigned int*)g,
      (__attribute__((address_space(3))) unsigned int*)l,
      16, 0, 0);
}

// ---- LDS XOR swizzle for [row][32-elem] tiles staged via global_load_lds ----
// Slot s (16B) of row R holds global chunk s ^ (R&3) ^ ((R>>2)&3).
// Staging: lane L covers (row = base + L/4); it must FETCH global chunk
//   (L&3) ^ ((L>>2)&3) ^ ((L>>4)&3)   [since LDS slot of lane L is L&3].
// Reading chunk q of row R': elem offset = (q ^ (c&3) ^ ((c>>2)&3)) * 8.
// Result: worst case 2 lanes/bank per b128 phase == conflict-free (m136).
__device__ __forceinline__ int swz_stage_col(int lane) {
  return (((lane & 3) ^ ((lane >> 2) & 3) ^ ((lane >> 4) & 3))) * 8;
}

// ---------------- conversion kernels ----------------

__global__ void cast_f32_bf16(const float* __restrict__ in, bf16* __restrict__ out, int n4) {
  int i = blockIdx.x * blockDim.x + threadIdx.x;
  if (i < n4) {
    float4 v = ((const float4*)in)[i];
    bf16x4 o = {(bf16)v.x, (bf16)v.y, (bf16)v.z, (bf16)v.w};
    ((bf16x4*)out)[i] = o;
  }
}

// in: R x C f32 (row-major). out: C x R bf16, row stride out_stride.
__global__ void transpose_cast(const float* __restrict__ in, bf16* __restrict__ out,
                               int R, int C, int out_stride) {
  __shared__ float tile[64][65];
  int r0 = blockIdx.x * 64, c0 = blockIdx.y * 64;
  int tx = threadIdx.x & 63, ty = threadIdx.x >> 6;
  for (int i = ty; i < 64; i += 4)
    tile[i][tx] = in[(size_t)(r0 + i) * C + c0 + tx];
  __syncthreads();
  for (int i = ty; i < 64; i += 4)
    out[(size_t)(c0 + i) * out_stride + r0 + tx] = (bf16)tile[tx][i];
}

__global__ void concat_bias(const float* __restrict__ bq, const float* __restrict__ bkv,
                            float* __restrict__ out) {
  int i = blockIdx.x * 256 + threadIdx.x;  // grid covers exactly 3072
  out[i] = (i < NQ) ? bq[i] : bkv[i - NQ];
}

// ---------------- GEMM: C = A(MxK) * Bt(NxK)^T (+bias) ----------------
// m97 structure: 128x128 tile, BK=32, global_load_lds width16, 16x16x32 MFMA,
// + XOR-swizzled LDS chunks (removes the 8-way bank conflict of stride-64B rows).

template <int OUT_BF16, int HAS_BIAS>
__global__ __launch_bounds__(256, 2) void gemm_bt(
    const bf16* __restrict__ A, const bf16* __restrict__ Bt,
    const float* __restrict__ bias, void* __restrict__ Cout,
    int M, int N, int K) {
  __shared__ __align__(16) bf16 As[128 * 32];
  __shared__ __align__(16) bf16 Bs[128 * 32];
  const int tid = threadIdx.x;
  const int wave = tid >> 6, lane = tid & 63;
  const int quad = lane >> 4, c = lane & 15;
  const int m0 = blockIdx.x * 128, n0 = blockIdx.y * 128;
  const int wr = (wave >> 1) * 64, wc = (wave & 1) * 64;
  const int xsl = ((quad ^ (c & 3) ^ ((c >> 2) & 3)) & 3) * 8;  // swizzled read slot

  floatx4 acc[4][4];
#pragma unroll
  for (int i = 0; i < 4; ++i)
#pragma unroll
    for (int j = 0; j < 4; ++j) acc[i][j] = (floatx4){0.f, 0.f, 0.f, 0.f};

  // staging: chunk = wave*2+ch covers 16 rows; lane -> row L/4, col swizzled
  const int srow = wave * 32 + (lane >> 2);
  const int scol = swz_stage_col(lane);
  const bf16* Ap = A + (size_t)(m0 + srow) * K + scol;
  const bf16* Bp = Bt + (size_t)(n0 + srow) * K + scol;

  for (int k0 = 0; k0 < K; k0 += 32) {
#pragma unroll
    for (int ch = 0; ch < 2; ++ch) {
      gload_lds16(Ap + (size_t)ch * 16 * K + k0, &As[(wave * 2 + ch) * 512]);
      gload_lds16(Bp + (size_t)ch * 16 * K + k0, &Bs[(wave * 2 + ch) * 512]);
    }
    __syncthreads();
    bf16x8 af[4], bfr[4];
#pragma unroll
    for (int i = 0; i < 4; ++i) {
      af[i]  = *(const bf16x8*)(&As[(wr + i * 16 + c) * 32 + xsl]);
      bfr[i] = *(const bf16x8*)(&Bs[(wc + i * 16 + c) * 32 + xsl]);
    }
#pragma unroll
    for (int mi = 0; mi < 4; ++mi)
#pragma unroll
      for (int ni = 0; ni < 4; ++ni)
        acc[mi][ni] = __builtin_amdgcn_mfma_f32_16x16x32_bf16(af[mi], bfr[ni], acc[mi][ni], 0, 0, 0);
    __syncthreads();
  }

  float bv[4] = {0.f, 0.f, 0.f, 0.f};
  if (HAS_BIAS) {
#pragma unroll
    for (int ni = 0; ni < 4; ++ni) bv[ni] = bias[n0 + wc + ni * 16 + c];
  }
#pragma unroll
  for (int mi = 0; mi < 4; ++mi) {
#pragma unroll
    for (int ni = 0; ni < 4; ++ni) {
      const int col = n0 + wc + ni * 16 + c;
#pragma unroll
      for (int r = 0; r < 4; ++r) {
        const int row = m0 + wr + mi * 16 + quad * 4 + r;  // C-layout: row=quad*4+reg
        float v = acc[mi][ni][r] + bv[ni];
        if (OUT_BF16)
          ((bf16*)Cout)[(size_t)row * N + col] = (bf16)v;
        else
          ((float*)Cout)[(size_t)row * N + col] = v;
      }
    }
  }
}

// ---------------- PE + layout scatter ----------------

__device__ __forceinline__ float pe_val(int t, int d) {
  int i2 = d & ~1;
  float inv = __expf(-9.210340371976184f * (float)i2 * (1.0f / 128.0f));
  float ang = (float)t * inv;
  return (d & 1) ? cosf(ang) : sinf(ang);
}

// Q[b][h][t][d] = (qkv[.., h*D+d] + pe) * log2(e)/sqrt(D)   (exp2-domain fold)
// K[b][g][t][d] =  qkv[.., 2048 + g*256 + d] + pe
__global__ void scatter_qk(const bf16* __restrict__ qkv,
                           bf16* __restrict__ Qb, bf16* __restrict__ Kb) {
  const int row = blockIdx.x;  // 0..4095
  const int b = row >> 11, t = row & 2047;
  const int tid = threadIdx.x;
  const int d = tid & 127;
  const float scale = 0.12751745f;  // log2(e)/sqrt(128)
  const float pe = pe_val(t, d);
  for (int h = tid >> 7; h < H_; h += 2) {
    float q = (float)qkv[(size_t)row * NQKV + h * 128 + d] + pe;
    Qb[((size_t)(b * H_ + h) * T_ + t) * D_ + d] = (bf16)(q * scale);
  }
  for (int g = tid >> 7; g < G_; g += 2) {
    float k = (float)qkv[(size_t)row * NQKV + NQ + g * 256 + d] + pe;
    Kb[((size_t)(b * G_ + g) * T_ + t) * D_ + d] = (bf16)k;
  }
}

// Vt[b][g][d][t] = qkv[b*T+t][2048 + g*256 + 128 + d]  (LDS-tiled transpose)
__global__ void build_vt(const bf16* __restrict__ qkv, bf16* __restrict__ Vt) {
  __shared__ float tile[64][65];
  int t0 = blockIdx.x * 64, d0 = blockIdx.y * 64;
  int bg = blockIdx.z, b = bg >> 2, g = bg & 3;
  const bf16* src = qkv + (size_t)b * T_ * NQKV + NQ + g * 256 + 128;
  bf16* dst = Vt + (size_t)bg * D_ * T_;
  int tx = threadIdx.x & 63, ty = threadIdx.x >> 6;
  for (int i = ty; i < 64; i += 4)
    tile[i][tx] = (float)src[(size_t)(t0 + i) * NQKV + d0 + tx];
  __syncthreads();
  for (int i = ty; i < 64; i += 4)
    dst[(size_t)(d0 + i) * T_ + t0 + tx] = (bf16)tile[tx][i];
}

// ---------------- flash attention v9 ----------------
// v7 closed its LDS-pipe roofline model (~276 LDS-cyc per 16q-tile-wave vs 78
// MFMA-cyc). v9 halves LDS read traffic per unit work: each wave owns 32 q
// (two 16-row halves) so every kf/vf b128 read feeds 2 MFMAs -- while KEEPING
// v7's 2-group key split, 512 threads, 75.8KB LDS, 2 blocks/CU = 4 waves/SIMD
// (v6 lost because it dropped to 2/SIMD; v8 lost because direct-V had no
// prefetch + 4KB-stride L2 pathology). Block covers 128 q-rows; 512 blocks,
// lengths 2(t+1)<=32, decode pairs t with 15-t at id/id+256 so per-CU sums
// are constant. P buffer is time-shared between halves (in-order DS) and
// XOR-swizzled (chunk^=quad) -> P-writes <=2-way, pf read conflict-free.

__global__ __launch_bounds__(512, 4) void flash_attn(
    const bf16* __restrict__ Qb, const bf16* __restrict__ Kb,
    const bf16* __restrict__ Vt, bf16* __restrict__ Ob) {
  const int i = blockIdx.x;
  const int tpos = i >> 5, bh = i & 31;
  const int t = (tpos < 8) ? tpos : 23 - tpos;  // q-chunk 0..15; pairs sum 15
  const int b = bh >> 4, h = bh & 15, g2 = h >> 2;
  const int tid = threadIdx.x;
  const int wave = tid >> 6, lane = tid & 63;
  const int grp = wave >> 2, w4 = wave & 3;   // key-range group, wave-in-group
  const int quad = lane >> 4, c = lane & 15;
  const int xsl = ((quad ^ (c & 3) ^ ((c >> 2) & 3)) & 3) * 8;  // swizzled read slot

  // 75,776 B static LDS; 2 blocks/CU (151,552 <= 163,840)
  __shared__ __align__(16) char smem[75776];
  bf16* Ks = (bf16*)smem;                  // [grp][buf][chunk4][32*32]  32 KB
  bf16* Vs = (bf16*)(smem + 32768);        // [grp][buf][chunk4][32*32]  32 KB
  bf16* Pq = (bf16*)(smem + 65536);        // [wave8][16*40] time-shared 10 KB

  const int q0 = t * 128;
  // two 16-row halves per wave: rows q0 + w4*32 + hf*16 + quad*4 + r
  bf16x8 qf[2][4];
#pragma unroll
  for (int hf = 0; hf < 2; ++hf) {
    const bf16* Qbase = Qb + ((size_t)(b * H_ + h) * T_ + q0 + w4 * 32 + hf * 16 + c) * D_;
#pragma unroll
    for (int ks = 0; ks < 4; ++ks)
      qf[hf][ks] = *(const bf16x8*)(Qbase + ks * 32 + quad * 8);
  }

  floatx4 acc[2][8];
#pragma unroll
  for (int hf = 0; hf < 2; ++hf)
#pragma unroll
    for (int nd = 0; nd < 8; ++nd) acc[hf][nd] = (floatx4){0.f, 0.f, 0.f, 0.f};
  float rsum[2][4] = {{0.f, 0.f, 0.f, 0.f}, {0.f, 0.f, 0.f, 0.f}};

  const bf16* Kg = Kb + (size_t)(b * G_ + g2) * T_ * D_;
  const bf16* Vg = Vt + (size_t)(b * G_ + g2) * D_ * T_;
  const int slr = lane >> 2;               // staging row within 16
  const int slc = swz_stage_col(lane);     // staging col (elems), swizzled
  const int ng = 2 * (t + 1);              // tiles per group
  const int jbase = grp * ng;              // group's first absolute key-tile
  const int amax = 4 * t + w4;             // wave's last live absolute tile

  // stage absolute key-tile tt into this group's buffer bu; wave owns chunk w4
  auto stage = [&](int tt, int bu) {
    const int k0 = tt * 32;
    bf16* kd = Ks + ((grp * 2 + bu) * 4 + w4) * 1024;
    bf16* vd = Vs + ((grp * 2 + bu) * 4 + w4) * 1024;
#pragma unroll
    for (int hh = 0; hh < 2; ++hh) {
      gload_lds16(Kg + (size_t)(k0 + hh * 16 + slr) * D_ + w4 * 32 + slc, kd + hh * 512);
      gload_lds16(Vg + (size_t)(w4 * 32 + hh * 16 + slr) * T_ + k0 + slc, vd + hh * 512);
    }
  };

  stage(jbase, 0);

  for (int jg = 0; jg < ng; ++jg) {
    __syncthreads();  // both groups run identical barrier counts (ng each)
    if (jg + 1 < ng) stage(jbase + jg + 1, (jg + 1) & 1);
    const int j = jbase + jg;
    if (j > amax) continue;  // fully masked for this wave: stage+barrier only

    const bf16* Kt  = Ks + (grp * 2 + (jg & 1)) * 4096;
    const bf16* Vtl = Vs + (grp * 2 + (jg & 1)) * 4096;

    // S = Q K^T : 2 x (16q x 32k) per wave, kf shared across halves
    floatx4 s[2][2];
#pragma unroll
    for (int hf = 0; hf < 2; ++hf)
#pragma unroll
      for (int n = 0; n < 2; ++n) s[hf][n] = (floatx4){0.f, 0.f, 0.f, 0.f};
#pragma unroll
    for (int ks = 0; ks < 4; ++ks)
#pragma unroll
      for (int n = 0; n < 2; ++n) {
        bf16x8 kf = *(const bf16x8*)(Kt + ks * 1024 + (n * 16 + c) * 32 + xsl);
        s[0][n] = __builtin_amdgcn_mfma_f32_16x16x32_bf16(qf[0][ks], kf, s[0][n], 0, 0, 0);
        s[1][n] = __builtin_amdgcn_mfma_f32_16x16x32_bf16(qf[1][ks], kf, s[1][n], 0, 0, 0);
      }

    if (j == amax) {  // diagonal tile: mask key > qrow (exp2(-1e30) == 0)
      const int colb = j * 32;
#pragma unroll
      for (int hf = 0; hf < 2; ++hf) {
        const int rowb = q0 + w4 * 32 + hf * 16 + quad * 4;
#pragma unroll
        for (int n = 0; n < 2; ++n)
#pragma unroll
          for (int r = 0; r < 4; ++r)
            if (colb + n * 16 + c > rowb + r) s[hf][n][r] = -1e30f;
      }
    }

    // p = exp2(s); P buffer time-shared between halves (DS ops are in-order
    // within a wave, so read pf0 before the hf=1 writes is safe).
    // Write swizzle: 16B-chunk (n*2 + c/8) XOR row-quad -> <=2-way banks.
    bf16* Pw = Pq + wave * 640;
    bf16x8 pf[2];
#pragma unroll
    for (int hf = 0; hf < 2; ++hf) {
#pragma unroll
      for (int n = 0; n < 2; ++n)
#pragma unroll
        for (int r = 0; r < 4; ++r) {
          float p = exp2f(s[hf][n][r]);
          rsum[hf][r] += p;
          const int chs = (n * 2 + (c >> 3)) ^ quad;
          Pw[(quad * 4 + r) * 40 + chs * 8 + (c & 7)] = (bf16)p;
        }
      // A-frag read: row c, chunk quad lives at slot quad ^ ((c>>2)&3)
      pf[hf] = *(const bf16x8*)(&Pw[c * 40 + ((quad ^ ((c >> 2) & 3))) * 8]);
    }

    // O += P(2 x 16q x 32k) * V(32k x 128d), vf shared across halves
#pragma unroll
    for (int nd = 0; nd < 8; ++nd) {
      bf16x8 vf = *(const bf16x8*)(Vtl + (nd >> 1) * 1024 + ((nd & 1) * 16 + c) * 32 + xsl);
      acc[0][nd] = __builtin_amdgcn_mfma_f32_16x16x32_bf16(pf[0], vf, acc[0][nd], 0, 0, 0);
      acc[1][nd] = __builtin_amdgcn_mfma_f32_16x16x32_bf16(pf[1], vf, acc[1][nd], 0, 0, 0);
    }
  }

  // per-group row-sum reduction across the 16 lanes (c) of each quad-row
#pragma unroll
  for (int off = 1; off < 16; off <<= 1)
#pragma unroll
    for (int hf = 0; hf < 2; ++hf)
#pragma unroll
      for (int r = 0; r < 4; ++r) rsum[hf][r] += __shfl_xor(rsum[hf][r], off);

  // ---- in-LDS merge of the two key-range groups (purely additive) ----
  __syncthreads();  // all loop LDS reads done; safe to alias Ks/Vs/Pq region
  float* mrg = (float*)smem;               // [2][128][68] f32, 69,632 B
  float* mrs = (float*)(smem + 69632);     // [2][128] f32 row-sums, 1 KB
  const int rw = w4 * 32 + quad * 4;       // + hf*16 + r

  // group g stashes the half it will NOT finalize
  if (grp == 0) {
#pragma unroll
    for (int hf = 0; hf < 2; ++hf)
#pragma unroll
      for (int nd2 = 0; nd2 < 4; ++nd2)
#pragma unroll
        for (int r = 0; r < 4; ++r)
          mrg[(size_t)(rw + hf * 16 + r) * 68 + nd2 * 16 + c] = acc[hf][4 + nd2][r];
  } else {
#pragma unroll
    for (int hf = 0; hf < 2; ++hf)
#pragma unroll
      for (int nd2 = 0; nd2 < 4; ++nd2)
#pragma unroll
        for (int r = 0; r < 4; ++r)
          mrg[(size_t)(128 + rw + hf * 16 + r) * 68 + nd2 * 16 + c] = acc[hf][nd2][r];
  }
  if (c == 0) {
#pragma unroll
    for (int hf = 0; hf < 2; ++hf)
#pragma unroll
      for (int r = 0; r < 4; ++r) mrs[grp * 128 + rw + hf * 16 + r] = rsum[hf][r];
  }
  __syncthreads();

  const int og = grp ^ 1;
#pragma unroll
  for (int hf = 0; hf < 2; ++hf) {
    float linv[4];
#pragma unroll
    for (int r = 0; r < 4; ++r)
      linv[r] = 1.f / (rsum[hf][r] + mrs[og * 128 + rw + hf * 16 + r]);
    if (grp == 0) {  // finalize cols 0..63 with group 1's copy
#pragma unroll
      for (int nd2 = 0; nd2 < 4; ++nd2)
#pragma unroll
        for (int r = 0; r < 4; ++r) {
          float o = acc[hf][nd2][r] + mrg[(size_t)(128 + rw + hf * 16 + r) * 68 + nd2 * 16 + c];
          const int trow = q0 + rw + hf * 16 + r;
          Ob[((size_t)(b * T_ + trow)) * NQ + h * D_ + nd2 * 16 + c] = (bf16)(o * linv[r]);
        }
    } else {         // finalize cols 64..127 with group 0's copy
#pragma unroll
      for (int nd2 = 0; nd2 < 4; ++nd2)
#pragma unroll
        for (int r = 0; r < 4; ++r) {
          float o = acc[hf][4 + nd2][r] + mrg[(size_t)(rw + hf * 16 + r) * 68 + nd2 * 16 + c];
          const int trow = q0 + rw + hf * 16 + r;
          Ob[((size_t)(b * T_ + trow)) * NQ + h * D_ + (4 + nd2) * 16 + c] = (bf16)(o * linv[r]);
        }
    }
  }
}

// ---------------- launch ----------------

extern "C" void kernel_launch(void* const* d_in, const int* in_sizes, int n_in,
                              void* d_out, int out_size, void* d_ws, size_t ws_size,
                              hipStream_t stream) {
  const float* x   = (const float*)d_in[0];
  const float* wq  = (const float*)d_in[1];
  const float* bq  = (const float*)d_in[2];
  const float* wkv = (const float*)d_in[3];
  const float* bkv = (const float*)d_in[4];
  const float* wo  = (const float*)d_in[5];
  float* out = (float*)d_out;

  char* p = (char*)d_ws;                                   // ~100 MB total
  bf16* xb    = (bf16*)p; p += (size_t)M_ * E_ * 2;        // 16 MB
  bf16* wqkvT = (bf16*)p; p += (size_t)NQKV * E_ * 2;      // 12 MB  [N=3072][K=2048]
  bf16* woT   = (bf16*)p; p += (size_t)E_ * NQ * 2;        // 8 MB   [N=2048][K=2048]
  float* biasq = (float*)p; p += 16384;                    // 3072 f32, padded
  bf16* qkv   = (bf16*)p; p += (size_t)M_ * NQKV * 2;      // 24 MB
  bf16* Qb    = (bf16*)p; p += (size_t)B_ * H_ * T_ * D_ * 2;  // 16 MB
  bf16* Kb    = (bf16*)p; p += (size_t)B_ * G_ * T_ * D_ * 2;  // 4 MB
  bf16* Vtb   = (bf16*)p; p += (size_t)B_ * G_ * D_ * T_ * 2;  // 4 MB
  bf16* Ob    = (bf16*)p; p += (size_t)M_ * NQ * 2;            // 16 MB

  cast_f32_bf16<<<(M_ * E_ / 4) / 256, 256, 0, stream>>>(x, xb, M_ * E_ / 4);
  transpose_cast<<<dim3(E_ / 64, E_ / 64), 256, 0, stream>>>(wq, wqkvT, E_, E_, E_);
  transpose_cast<<<dim3(E_ / 64, NKV / 64), 256, 0, stream>>>(wkv, wqkvT + (size_t)NQ * E_, E_, NKV, E_);
  transpose_cast<<<dim3(E_ / 64, E_ / 64), 256, 0, stream>>>(wo, woT, NQ, E_, NQ);
  concat_bias<<<NQKV / 256, 256, 0, stream>>>(bq, bkv, biasq);

  gemm_bt<1, 1><<<dim3(M_ / 128, NQKV / 128), 256, 0, stream>>>(xb, wqkvT, biasq, qkv, M_, NQKV, E_);
  scatter_qk<<<M_, 256, 0, stream>>>(qkv, Qb, Kb);
  build_vt<<<dim3(T_ / 64, D_ / 64, B_ * G_), 256, 0, stream>>>(qkv, Vtb);
  flash_attn<<<512, 512, 0, stream>>>(Qb, Kb, Vtb, Ob);
  gemm_bt<0, 0><<<dim3(M_ / 128, E_ / 128), 256, 0, stream>>>(Ob, woT, nullptr, out, M_, E_, NQ);
}

// Round 6
// 312.739 us; speedup vs baseline: 1.3556x; 1.1669x over previous
//
#include <hip/hip_runtime.h>
#include <stdint.h>

typedef __bf16 bf16;
typedef __bf16 bf16x4 __attribute__((ext_vector_type(4)));
typedef __bf16 bf16x8 __attribute__((ext_vector_type(8)));
typedef float floatx4 __attribute__((ext_vector_type(4)));

#define B_   2
#define T_   2048
#define E_   2048
#define G_   4
#define QPG_ 4
#define D_   128
#define H_   16        // G*QPG
#define NQ   2048      // H*D
#define NKV  1024      // 2*G*D
#define NQKV 3072
#define M_   4096      // B*T

// async global->LDS, 16B/lane; LDS dst is wave-uniform base + lane*16
__device__ __forceinline__ void gload_lds16(const void* g, void* l) {
  __builtin_amdgcn_global_load_lds(
      (__attribute__((address_space(1))) unsigned int*)g,
      (__attribute__((address_space(3))) unsigned int*)l,
      16, 0, 0);
}

// ---- LDS XOR swizzle for [row][32-elem] tiles staged via global_load_lds ----
// Slot s (16B) of row R holds global chunk s ^ (R&3) ^ ((R>>2)&3).
// Staging: lane L covers (row = base + L/4); it must FETCH global chunk
//   (L&3) ^ ((L>>2)&3) ^ ((L>>4)&3)   [since LDS slot of lane L is L&3].
// Reading chunk q of row R': elem offset = (q ^ (c&3) ^ ((c>>2)&3)) * 8.
// Result: worst case 2 lanes/bank per b128 phase == conflict-free (m136).
__device__ __forceinline__ int swz_stage_col(int lane) {
  return (((lane & 3) ^ ((lane >> 2) & 3) ^ ((lane >> 4) & 3))) * 8;
}

// ---------------- conversion kernels ----------------

__global__ void cast_f32_bf16(const float* __restrict__ in, bf16* __restrict__ out, int n4) {
  int i = blockIdx.x * blockDim.x + threadIdx.x;
  if (i < n4) {
    float4 v = ((const float4*)in)[i];
    bf16x4 o = {(bf16)v.x, (bf16)v.y, (bf16)v.z, (bf16)v.w};
    ((bf16x4*)out)[i] = o;
  }
}

// in: R x C f32 (row-major). out: C x R bf16, row stride out_stride.
__global__ void transpose_cast(const float* __restrict__ in, bf16* __restrict__ out,
                               int R, int C, int out_stride) {
  __shared__ float tile[64][65];
  int r0 = blockIdx.x * 64, c0 = blockIdx.y * 64;
  int tx = threadIdx.x & 63, ty = threadIdx.x >> 6;
  for (int i = ty; i < 64; i += 4)
    tile[i][tx] = in[(size_t)(r0 + i) * C + c0 + tx];
  __syncthreads();
  for (int i = ty; i < 64; i += 4)
    out[(size_t)(c0 + i) * out_stride + r0 + tx] = (bf16)tile[tx][i];
}

__global__ void concat_bias(const float* __restrict__ bq, const float* __restrict__ bkv,
                            float* __restrict__ out) {
  int i = blockIdx.x * 256 + threadIdx.x;  // grid covers exactly 3072
  out[i] = (i < NQ) ? bq[i] : bkv[i - NQ];
}

// ---------------- GEMM: C = A(MxK) * Bt(NxK)^T (+bias) ----------------
// m97 structure: 128x128 tile, BK=32, global_load_lds width16, 16x16x32 MFMA,
// + XOR-swizzled LDS chunks (removes the 8-way bank conflict of stride-64B rows).

template <int OUT_BF16, int HAS_BIAS>
__global__ __launch_bounds__(256, 2) void gemm_bt(
    const bf16* __restrict__ A, const bf16* __restrict__ Bt,
    const float* __restrict__ bias, void* __restrict__ Cout,
    int M, int N, int K) {
  __shared__ __align__(16) bf16 As[128 * 32];
  __shared__ __align__(16) bf16 Bs[128 * 32];
  const int tid = threadIdx.x;
  const int wave = tid >> 6, lane = tid & 63;
  const int quad = lane >> 4, c = lane & 15;
  const int m0 = blockIdx.x * 128, n0 = blockIdx.y * 128;
  const int wr = (wave >> 1) * 64, wc = (wave & 1) * 64;
  const int xsl = ((quad ^ (c & 3) ^ ((c >> 2) & 3)) & 3) * 8;  // swizzled read slot

  floatx4 acc[4][4];
#pragma unroll
  for (int i = 0; i < 4; ++i)
#pragma unroll
    for (int j = 0; j < 4; ++j) acc[i][j] = (floatx4){0.f, 0.f, 0.f, 0.f};

  // staging: chunk = wave*2+ch covers 16 rows; lane -> row L/4, col swizzled
  const int srow = wave * 32 + (lane >> 2);
  const int scol = swz_stage_col(lane);
  const bf16* Ap = A + (size_t)(m0 + srow) * K + scol;
  const bf16* Bp = Bt + (size_t)(n0 + srow) * K + scol;

  for (int k0 = 0; k0 < K; k0 += 32) {
#pragma unroll
    for (int ch = 0; ch < 2; ++ch) {
      gload_lds16(Ap + (size_t)ch * 16 * K + k0, &As[(wave * 2 + ch) * 512]);
      gload_lds16(Bp + (size_t)ch * 16 * K + k0, &Bs[(wave * 2 + ch) * 512]);
    }
    __syncthreads();
    bf16x8 af[4], bfr[4];
#pragma unroll
    for (int i = 0; i < 4; ++i) {
      af[i]  = *(const bf16x8*)(&As[(wr + i * 16 + c) * 32 + xsl]);
      bfr[i] = *(const bf16x8*)(&Bs[(wc + i * 16 + c) * 32 + xsl]);
    }
#pragma unroll
    for (int mi = 0; mi < 4; ++mi)
#pragma unroll
      for (int ni = 0; ni < 4; ++ni)
        acc[mi][ni] = __builtin_amdgcn_mfma_f32_16x16x32_bf16(af[mi], bfr[ni], acc[mi][ni], 0, 0, 0);
    __syncthreads();
  }

  float bv[4] = {0.f, 0.f, 0.f, 0.f};
  if (HAS_BIAS) {
#pragma unroll
    for (int ni = 0; ni < 4; ++ni) bv[ni] = bias[n0 + wc + ni * 16 + c];
  }
#pragma unroll
  for (int mi = 0; mi < 4; ++mi) {
#pragma unroll
    for (int ni = 0; ni < 4; ++ni) {
      const int col = n0 + wc + ni * 16 + c;
#pragma unroll
      for (int r = 0; r < 4; ++r) {
        const int row = m0 + wr + mi * 16 + quad * 4 + r;  // C-layout: row=quad*4+reg
        float v = acc[mi][ni][r] + bv[ni];
        if (OUT_BF16)
          ((bf16*)Cout)[(size_t)row * N + col] = (bf16)v;
        else
          ((float*)Cout)[(size_t)row * N + col] = v;
      }
    }
  }
}

// ---------------- PE + layout scatter ----------------

__device__ __forceinline__ float pe_val(int t, int d) {
  int i2 = d & ~1;
  float inv = __expf(-9.210340371976184f * (float)i2 * (1.0f / 128.0f));
  float ang = (float)t * inv;
  return (d & 1) ? cosf(ang) : sinf(ang);
}

// Q[b][h][t][d] = (qkv[.., h*D+d] + pe) * log2(e)/sqrt(D)   (exp2-domain fold)
// K[b][g][t][d] =  qkv[.., 2048 + g*256 + d] + pe
__global__ void scatter_qk(const bf16* __restrict__ qkv,
                           bf16* __restrict__ Qb, bf16* __restrict__ Kb) {
  const int row = blockIdx.x;  // 0..4095
  const int b = row >> 11, t = row & 2047;
  const int tid = threadIdx.x;
  const int d = tid & 127;
  const float scale = 0.12751745f;  // log2(e)/sqrt(128)
  const float pe = pe_val(t, d);
  for (int h = tid >> 7; h < H_; h += 2) {
    float q = (float)qkv[(size_t)row * NQKV + h * 128 + d] + pe;
    Qb[((size_t)(b * H_ + h) * T_ + t) * D_ + d] = (bf16)(q * scale);
  }
  for (int g = tid >> 7; g < G_; g += 2) {
    float k = (float)qkv[(size_t)row * NQKV + NQ + g * 256 + d] + pe;
    Kb[((size_t)(b * G_ + g) * T_ + t) * D_ + d] = (bf16)k;
  }
}

// Vt[b][g][d][t] = qkv[b*T+t][2048 + g*256 + 128 + d]  (LDS-tiled transpose)
__global__ void build_vt(const bf16* __restrict__ qkv, bf16* __restrict__ Vt) {
  __shared__ float tile[64][65];
  int t0 = blockIdx.x * 64, d0 = blockIdx.y * 64;
  int bg = blockIdx.z, b = bg >> 2, g = bg & 3;
  const bf16* src = qkv + (size_t)b * T_ * NQKV + NQ + g * 256 + 128;
  bf16* dst = Vt + (size_t)bg * D_ * T_;
  int tx = threadIdx.x & 63, ty = threadIdx.x >> 6;
  for (int i = ty; i < 64; i += 4)
    tile[i][tx] = (float)src[(size_t)(t0 + i) * NQKV + d0 + tx];
  __syncthreads();
  for (int i = ty; i < 64; i += 4)
    dst[(size_t)(d0 + i) * T_ + t0 + tx] = (bf16)tile[tx][i];
}

// ---------------- flash attention v10: equal-work blocks ----------------
// v7's cycle model closed (LDS pipe ~146K cyc of 189K measured); the ~23%
// gap is makespan/tail (occupancy 36%, block lengths 1..32 tiles, scheduler
// pairing unknown). v9 proved 32q/wave spills (VGPR 64 < demand ~150, HBM
// +83MB scratch traffic). v10 = v7's exact per-tile structure, but each
// block processes TWO q-tiles (p and 31-p) sequentially: per-group length
// (p+1)+(32-p) = 33 tiles for EVERY block. 512 blocks = exactly 2/CU
// resident (4 waves/SIMD, VGPR 52, no spill), deterministic per-CU work,
// zero tail, scheduler-pairing-independent.

__global__ __launch_bounds__(512, 4) void flash_attn(
    const bf16* __restrict__ Qb, const bf16* __restrict__ Kb,
    const bf16* __restrict__ Vt, bf16* __restrict__ Ob) {
  const int i = blockIdx.x;
  const int p = i >> 5;           // 0..15
  const int bh = i & 31;
  const int b = bh >> 4, h = bh & 15, g2 = h >> 2;
  const int tid = threadIdx.x;
  const int wave = tid >> 6, lane = tid & 63;
  const int grp = wave >> 2, w4 = wave & 3;   // key-range group, wave-in-group
  const int quad = lane >> 4, c = lane & 15;
  const int xsl = ((quad ^ (c & 3) ^ ((c >> 2) & 3)) & 3) * 8;  // swizzled read slot

  // 75,776 B static LDS; 2 blocks/CU (151,552 <= 163,840)
  __shared__ __align__(16) char smem[75776];
  bf16* Ks = (bf16*)smem;                  // [grp][buf][chunk4][32*32]  32 KB
  bf16* Vs = (bf16*)(smem + 32768);        // [grp][buf][chunk4][32*32]  32 KB
  bf16* Pq = (bf16*)(smem + 65536);        // [wave8][16*40]             10 KB

  const bf16* Kg = Kb + (size_t)(b * G_ + g2) * T_ * D_;
  const bf16* Vg = Vt + (size_t)(b * G_ + g2) * D_ * T_;
  const int slr = lane >> 2;               // staging row within 16
  const int slc = swz_stage_col(lane);     // staging col (elems), swizzled

  // stage absolute key-tile tt into this group's buffer bu; wave owns chunk w4
  auto stage = [&](int tt, int bu) {
    const int k0 = tt * 32;
    bf16* kd = Ks + ((grp * 2 + bu) * 4 + w4) * 1024;
    bf16* vd = Vs + ((grp * 2 + bu) * 4 + w4) * 1024;
#pragma unroll
    for (int hh = 0; hh < 2; ++hh) {
      gload_lds16(Kg + (size_t)(k0 + hh * 16 + slr) * D_ + w4 * 32 + slc, kd + hh * 512);
      gload_lds16(Vg + (size_t)(w4 * 32 + hh * 16 + slr) * T_ + k0 + slc, vd + hh * 512);
    }
  };

  for (int ph = 0; ph < 2; ++ph) {
    const int qt = ph ? (31 - p) : p;
    const int q0 = qt * 64;
    if (ph) __syncthreads();  // phase-1 merge LDS reads done before restaging

    const bf16* Qbase = Qb + ((size_t)(b * H_ + h) * T_ + q0 + w4 * 16 + c) * D_;
    bf16x8 qf[4];
#pragma unroll
    for (int ks = 0; ks < 4; ++ks)
      qf[ks] = *(const bf16x8*)(Qbase + ks * 32 + quad * 8);

    floatx4 acc[8];
#pragma unroll
    for (int nd = 0; nd < 8; ++nd) acc[nd] = (floatx4){0.f, 0.f, 0.f, 0.f};
    float rsum[4] = {0.f, 0.f, 0.f, 0.f};

    const int ng = qt + 1;                 // tiles per group
    const int jbase = grp * ng;            // group's first absolute key-tile
    const int amax = 2 * qt + (w4 >> 1);   // wave's last live absolute tile

    stage(jbase, 0);

    for (int jg = 0; jg < ng; ++jg) {
      __syncthreads();  // buf[jg&1] ready; prev tile's LDS reads done
      if (jg + 1 < ng) stage(jbase + jg + 1, (jg + 1) & 1);
      const int j = jbase + jg;
      if (j > amax) continue;  // fully masked for this wave: stage+barrier only

      const bf16* Kt  = Ks + (grp * 2 + (jg & 1)) * 4096;
      const bf16* Vtl = Vs + (grp * 2 + (jg & 1)) * 4096;

      // S = Q K^T : 16q x 32k per wave (scores already in log2 domain)
      floatx4 s[2];
      s[0] = (floatx4){0.f, 0.f, 0.f, 0.f};
      s[1] = (floatx4){0.f, 0.f, 0.f, 0.f};
#pragma unroll
      for (int ks = 0; ks < 4; ++ks)
#pragma unroll
        for (int n = 0; n < 2; ++n) {
          bf16x8 kf = *(const bf16x8*)(Kt + ks * 1024 + (n * 16 + c) * 32 + xsl);
          s[n] = __builtin_amdgcn_mfma_f32_16x16x32_bf16(qf[ks], kf, s[n], 0, 0, 0);
        }

      if (j == amax) {  // diagonal tile: mask key > qrow (exp2(-1e30) == 0)
        const int colb = j * 32;
        const int rowb = q0 + w4 * 16 + quad * 4;
#pragma unroll
        for (int n = 0; n < 2; ++n)
#pragma unroll
          for (int r = 0; r < 4; ++r)
            if (colb + n * 16 + c > rowb + r) s[n][r] = -1e30f;
      }

      // p = exp2(s); accumulate row-sum; P to LDS in A-layout [q][key]
      bf16* Pw = Pq + wave * 640;
#pragma unroll
      for (int n = 0; n < 2; ++n)
#pragma unroll
        for (int r = 0; r < 4; ++r) {
          float pv = exp2f(s[n][r]);
          rsum[r] += pv;
          Pw[(quad * 4 + r) * 40 + n * 16 + c] = (bf16)pv;
        }

      // A-frag read: one aligned b128  (pf[j] = P[q=c][key=quad*8+j])
      bf16x8 pf = *(const bf16x8*)(&Pw[c * 40 + quad * 8]);

      // O += P(16q x 32k) * V(32k x 128d)
#pragma unroll
      for (int nd = 0; nd < 8; ++nd) {
        bf16x8 vf = *(const bf16x8*)(Vtl + (nd >> 1) * 1024 + ((nd & 1) * 16 + c) * 32 + xsl);
        acc[nd] = __builtin_amdgcn_mfma_f32_16x16x32_bf16(pf, vf, acc[nd], 0, 0, 0);
      }
    }

    // per-group row-sum reduction across the 16 lanes (c) of each quad-row
#pragma unroll
    for (int off = 1; off < 16; off <<= 1)
#pragma unroll
      for (int r = 0; r < 4; ++r) rsum[r] += __shfl_xor(rsum[r], off);

    // ---- in-LDS merge of the two key-range groups (purely additive) ----
    __syncthreads();  // all loop LDS reads done; safe to alias Ks/Vs region
    float* mrg = (float*)smem;               // [2][64][68] f32, 34,816 B
    float* mrs = (float*)(smem + 34816);     // [2][64] f32 row-sums
    const int row16 = w4 * 16 + quad * 4;

    // group g stashes the half it will NOT finalize: half (1-g)
    if (grp == 0) {
#pragma unroll
      for (int nd2 = 0; nd2 < 4; ++nd2)
#pragma unroll
        for (int r = 0; r < 4; ++r)
          mrg[(row16 + r) * 68 + nd2 * 16 + c] = acc[4 + nd2][r];
    } else {
#pragma unroll
      for (int nd2 = 0; nd2 < 4; ++nd2)
#pragma unroll
        for (int r = 0; r < 4; ++r)
          mrg[(64 + row16 + r) * 68 + nd2 * 16 + c] = acc[nd2][r];
    }
    if (c == 0) {
#pragma unroll
      for (int r = 0; r < 4; ++r) mrs[grp * 64 + row16 + r] = rsum[r];
    }
    __syncthreads();

    const int og = grp ^ 1;
    float linv[4];
#pragma unroll
    for (int r = 0; r < 4; ++r) linv[r] = 1.f / (rsum[r] + mrs[og * 64 + row16 + r]);

    if (grp == 0) {  // finalize cols 0..63 (nd 0..3) with group 1's copy
#pragma unroll
      for (int nd2 = 0; nd2 < 4; ++nd2)
#pragma unroll
        for (int r = 0; r < 4; ++r) {
          float o = acc[nd2][r] + mrg[(64 + row16 + r) * 68 + nd2 * 16 + c];
          const int trow = q0 + row16 + r;
          Ob[((size_t)(b * T_ + trow)) * NQ + h * D_ + nd2 * 16 + c] = (bf16)(o * linv[r]);
        }
    } else {         // finalize cols 64..127 (nd 4..7) with group 0's copy
#pragma unroll
      for (int nd2 = 0; nd2 < 4; ++nd2)
#pragma unroll
        for (int r = 0; r < 4; ++r) {
          float o = acc[4 + nd2][r] + mrg[(row16 + r) * 68 + nd2 * 16 + c];
          const int trow = q0 + row16 + r;
          Ob[((size_t)(b * T_ + trow)) * NQ + h * D_ + (4 + nd2) * 16 + c] = (bf16)(o * linv[r]);
        }
    }
  }
}

// ---------------- launch ----------------

extern "C" void kernel_launch(void* const* d_in, const int* in_sizes, int n_in,
                              void* d_out, int out_size, void* d_ws, size_t ws_size,
                              hipStream_t stream) {
  const float* x   = (const float*)d_in[0];
  const float* wq  = (const float*)d_in[1];
  const float* bq  = (const float*)d_in[2];
  const float* wkv = (const float*)d_in[3];
  const float* bkv = (const float*)d_in[4];
  const float* wo  = (const float*)d_in[5];
  float* out = (float*)d_out;

  char* p = (char*)d_ws;                                   // ~100 MB total
  bf16* xb    = (bf16*)p; p += (size_t)M_ * E_ * 2;        // 16 MB
  bf16* wqkvT = (bf16*)p; p += (size_t)NQKV * E_ * 2;      // 12 MB  [N=3072][K=2048]
  bf16* woT   = (bf16*)p; p += (size_t)E_ * NQ * 2;        // 8 MB   [N=2048][K=2048]
  float* biasq = (float*)p; p += 16384;                    // 3072 f32, padded
  bf16* qkv   = (bf16*)p; p += (size_t)M_ * NQKV * 2;      // 24 MB
  bf16* Qb    = (bf16*)p; p += (size_t)B_ * H_ * T_ * D_ * 2;  // 16 MB
  bf16* Kb    = (bf16*)p; p += (size_t)B_ * G_ * T_ * D_ * 2;  // 4 MB
  bf16* Vtb   = (bf16*)p; p += (size_t)B_ * G_ * D_ * T_ * 2;  // 4 MB
  bf16* Ob    = (bf16*)p; p += (size_t)M_ * NQ * 2;            // 16 MB

  cast_f32_bf16<<<(M_ * E_ / 4) / 256, 256, 0, stream>>>(x, xb, M_ * E_ / 4);
  transpose_cast<<<dim3(E_ / 64, E_ / 64), 256, 0, stream>>>(wq, wqkvT, E_, E_, E_);
  transpose_cast<<<dim3(E_ / 64, NKV / 64), 256, 0, stream>>>(wkv, wqkvT + (size_t)NQ * E_, E_, NKV, E_);
  transpose_cast<<<dim3(E_ / 64, E_ / 64), 256, 0, stream>>>(wo, woT, NQ, E_, NQ);
  concat_bias<<<NQKV / 256, 256, 0, stream>>>(bq, bkv, biasq);

  gemm_bt<1, 1><<<dim3(M_ / 128, NQKV / 128), 256, 0, stream>>>(xb, wqkvT, biasq, qkv, M_, NQKV, E_);
  scatter_qk<<<M_, 256, 0, stream>>>(qkv, Qb, Kb);
  build_vt<<<dim3(T_ / 64, D_ / 64, B_ * G_), 256, 0, stream>>>(qkv, Vtb);
  flash_attn<<<512, 512, 0, stream>>>(Qb, Kb, Vtb, Ob);
  gemm_bt<0, 0><<<dim3(M_ / 128, E_ / 128), 256, 0, stream>>>(Ob, woT, nullptr, out, M_, E_, NQ);
}